// Round 9
// baseline (444.858 us; speedup 1.0000x reference)
//
#include <hip/hip_runtime.h>
#include <stdint.h>

#define TOKENS 16384
#define D_IN   4096
#define D_OUT  4096
#define NKT    64   // K-tiles of 64 i8

typedef int v4i  __attribute__((ext_vector_type(4)));
typedef int v16i __attribute__((ext_vector_type(16)));

__device__ __forceinline__ void gl_lds16(const void* g, void* l) {
    __builtin_amdgcn_global_load_lds(
        (const __attribute__((address_space(1))) void*)g,
        (__attribute__((address_space(3))) void*)l, 16, 0, 0);
}

#define BARRIER() __builtin_amdgcn_s_barrier()

__device__ __forceinline__ unsigned sgnb(float f) {
    return (unsigned)(unsigned char)(signed char)((f > 0.f) - (f < 0.f));
}

// ---------------------------------------------------------------------------
// Packed image for 32x32x32 i8 MFMA fragments (UNCHANGED since R6; verified
// absmax=0, SQ_LDS_BANK_CONFLICT=0).
// A: [mb(128)][kt(64)][u(4)][ks(2)][1KB]  row = mb*128+u*32+r, k = kt*64+ks*32+..
// B: [nb(16)][kt(64)][u(8)][ks(2)][1KB]
// Every 1KB fragment is lane-linear (lane*16): one coalesced wave-load for
// gl_lds, ds_read_b128 AND global_load_dwordx4.
// ---------------------------------------------------------------------------

__global__ __launch_bounds__(256) void pack_x_abssum(
        const float* __restrict__ x, signed char* __restrict__ xp,
        float* __restrict__ partials) {
    __shared__ unsigned char img[16384];   // two 8KB kt-units
    __shared__ float wsum[4];
    const int b   = blockIdx.x;            // 128*32 = 4096 blocks
    const int mb  = b >> 5;
    const int kt2 = b & 31;
    const int t   = threadIdx.x;
    const float* src = x + (size_t)mb * 128 * D_IN + kt2 * 128;
    float accum = 0.f;
#pragma unroll
    for (int p = 0; p < 16; ++p) {
        const int idx = p * 256 + t;       // 128 rows x 32 float4
        const int r   = idx >> 5;
        const int c4  = idx & 31;
        float4 v = *(const float4*)(src + (size_t)r * D_IN + c4 * 4);
        unsigned w = sgnb(v.x) | (sgnb(v.y) << 8) | (sgnb(v.z) << 16) | (sgnb(v.w) << 24);
        const int kl = (c4 * 4) & 63;
        const int off = ((c4 >= 16) ? 8192 : 0)
                      + (r >> 5) * 2048 + (kl >> 5) * 1024 + ((kl >> 4) & 1) * 512
                      + (r & 31) * 16 + (kl & 15);
        *(unsigned*)&img[off] = w;
        accum += fabsf(v.x) + fabsf(v.y) + fabsf(v.z) + fabsf(v.w);
    }
    __syncthreads();
    unsigned* dst = (unsigned*)(xp + ((size_t)mb * 64 + kt2 * 2) * 8192);
    const unsigned* s32 = (const unsigned*)img;
#pragma unroll
    for (int p = 0; p < 16; ++p) dst[p * 256 + t] = s32[p * 256 + t];
#pragma unroll
    for (int o = 32; o > 0; o >>= 1) accum += __shfl_down(accum, o);
    if ((t & 63) == 0) wsum[t >> 6] = accum;
    __syncthreads();
    if (t == 0) partials[b] = wsum[0] + wsum[1] + wsum[2] + wsum[3];
}

__global__ void reduce_partials(const float* __restrict__ p, float* __restrict__ s) {
    __shared__ float ws[4];
    float a = 0.f;
    for (int i = threadIdx.x; i < 4096; i += 256) a += p[i];
#pragma unroll
    for (int o = 32; o > 0; o >>= 1) a += __shfl_down(a, o);
    if ((threadIdx.x & 63) == 0) ws[threadIdx.x >> 6] = a;
    __syncthreads();
    if (threadIdx.x == 0) s[0] = ws[0] + ws[1] + ws[2] + ws[3];
}

__global__ __launch_bounds__(256) void pack_w_kernel(
        const float* __restrict__ wsrc, signed char* __restrict__ wp) {
    __shared__ unsigned char img[16384];
    const int b  = blockIdx.x;             // 16*64 = 1024 blocks
    const int nb = b >> 6;
    const int kt = b & 63;
    const int t  = threadIdx.x;
    const float* src = wsrc + (size_t)nb * 256 * D_IN + kt * 64;
#pragma unroll
    for (int p = 0; p < 16; ++p) {
        const int idx = p * 256 + t;       // 256 rows x 16 float4
        const int r   = idx >> 4;
        const int c4  = idx & 15;
        float4 v = *(const float4*)(src + (size_t)r * D_IN + c4 * 4);
        unsigned w = sgnb(v.x) | (sgnb(v.y) << 8) | (sgnb(v.z) << 16) | (sgnb(v.w) << 24);
        const int kl = c4 * 4;
        const int off = (r >> 5) * 2048 + (kl >> 5) * 1024 + ((kl >> 4) & 1) * 512
                      + (r & 31) * 16 + (kl & 15);
        *(unsigned*)&img[off] = w;
    }
    __syncthreads();
    unsigned* dst = (unsigned*)(wp + ((size_t)nb * 64 + kt) * 16384);
    const unsigned* s32 = (const unsigned*)img;
#pragma unroll
    for (int p = 0; p < 16; ++p) dst[p * 256 + t] = s32[p * 256 + t];
}

// ---------------------------------------------------------------------------
// 128x256 tile, BK=64, 4 waves (2Mx2N), wave-tile 64x128, mfma_i32_32x32x32.
// R8's cross-barrier rotation + B DIRECT L2->VGPR (LDS de-saturation):
// R8 diagnosis: 96 ds_read_b128/CU/tile-slot ~= 1150 cyc saturates the
// CU-shared LDS pipe (~= the 1171-cyc MFMA floor) -> pipes serialize at
// ~2390 cyc. Moving B (2/3 of LDS reads) to direct global loads from the
// L2-resident slice drops LDS to ~390 cyc; B supply rides the L2 pipe
// (~80 KB/tile-slot @ 56 B/cyc/CU ~= 1430 cyc) overlapping MFMA.
// Rotation: Pb <- B-ks0(t+1) issued right after CLUSTER(P) frees it
// (consumed next iter: full-iteration cover); same for Qb after CLUSTER(Q).
// Counted waits (queue-walked): W1 vmcnt(6) [Pb(t) ready; leaves SA+Qb=6],
// W2 vmcnt(10) [SA(t+1) landed; leaves Qb+Pb'+SA'=10], W3 vmcnt(6)
// [Qb(t) ready]. Never drains. Uniform loop via &63 wrap staging.
// A stays in LDS (L3-sourced, dedupe mandatory), triple-buffered 3x8KB.
// ---------------------------------------------------------------------------

#define STAGE_A(d, kt) do {                                             \
    signed char* L_ = (signed char*)&ldsA[d][0];                        \
    const signed char* ga_ = aG + (size_t)((kt) & 63) * 8192;           \
    gl_lds16(ga_ + t16,        L_ + t16);                               \
    gl_lds16(ga_ + 4096 + t16, L_ + 4096 + t16);                       \
} while (0)

#define LOADB(dst, kt, ks) do {                                         \
    const signed char* g_ = bG0 + (size_t)((kt) & 63) * 16384 + (ks) * 1024; \
    dst[0] = *(const v4i*)(g_);                                         \
    dst[1] = *(const v4i*)(g_ + 2048);                                  \
    dst[2] = *(const v4i*)(g_ + 4096);                                  \
    dst[3] = *(const v4i*)(g_ + 6144);                                  \
} while (0)

#define READ_A(dst, bufv, ks) do {                                      \
    const v4i* L_ = &ldsA[bufv][0];                                     \
    dst[0] = L_[auo + (ks) * 64 + lane];                                \
    dst[1] = L_[auo + 128 + (ks) * 64 + lane];                          \
} while (0)

#define MFMA32(d, a, b) __builtin_amdgcn_mfma_i32_32x32x32_i8((a), (b), (d), 0, 0, 0)

#define CLUSTER(A2, B4) do {                                            \
    _Pragma("unroll")                                                   \
    for (int an = 0; an < 4; ++an) {                                    \
        acc[0][an] = MFMA32(acc[0][an], A2[0], B4[an]);                 \
        acc[1][an] = MFMA32(acc[1][an], A2[1], B4[an]);                 \
    }                                                                   \
} while (0)

__global__ __launch_bounds__(256, 2) void bin_gemm(
    const signed char* __restrict__ Ap, const signed char* __restrict__ Bp,
    const float* __restrict__ bias, const float* __restrict__ sum_ptr,
    float* __restrict__ out) {
    __shared__ v4i ldsA[3][512];           // 3 x 8KB = 24KB (A only)

    const int t    = threadIdx.x;          // 0..255
    const int t16  = t * 16;
    const int lane = t & 63;
    const int wid  = t >> 6;               // 0..3
    const int wm   = wid >> 1;             // M half: rows wm*64
    const int wn   = wid & 1;              // N half: cols wn*128
    const int auo  = (wm * 2) * 128;       // A v4i-offset base

    // XCD slice: xcd owns nb {2x,2x+1} (2MB packed B L2-resident).
    const int bid   = blockIdx.x;          // 2048 blocks
    const int xcd   = bid & 7;
    const int local = bid >> 3;            // 0..255
    const int nb    = xcd * 2 + (local & 1);
    const int mb    = local >> 1;          // 0..127

    const signed char* aG  = Ap + (size_t)mb * 64 * 8192;
    const signed char* bG0 = Bp + (size_t)nb * 64 * 16384
                                + (size_t)(wn * 4) * 2048 + lane * 16;

    v16i acc[2][4];
#pragma unroll
    for (int i = 0; i < 2; ++i)
#pragma unroll
        for (int j = 0; j < 4; ++j) acc[i][j] = (v16i)(0);

    v4i Pa[2], Qa[2], Pb[4], Qb[4];

    // prologue: SA0(2) SA1(2) Pb(4) Qb(4); vmcnt(4) ensures SA0,SA1,Pb done.
    STAGE_A(0, 0);
    STAGE_A(1, 1);
    LOADB(Pb, 0, 0);
    LOADB(Qb, 0, 1);
    asm volatile("s_waitcnt vmcnt(4)" ::: "memory");
    BARRIER();
    READ_A(Pa, 0, 0);
    READ_A(Qa, 0, 1);

    int cb = 0, rb = 1, sb = 2;
    for (int kt = 0; kt < NKT; ++kt) {
        // W1: Pb(kt) ready (steady queue: Pb4 SA2 Qb4 -> leave 6)
        asm volatile("s_waitcnt vmcnt(6)" ::: "memory");
        CLUSTER(Pa, Pb);                   // ks0(kt)
        LOADB(Pb, kt + 1, 0);              // -> consumed next iter (full cover)
        STAGE_A(sb, kt + 2);               // A(kt+2), wrap-staged at tail
        // W2: SA(kt+1) landed (queue: SA'2 Qb4 Pb4 SA''2 -> leave 10)
        asm volatile("s_waitcnt lgkmcnt(0)" ::: "memory");
        asm volatile("s_waitcnt vmcnt(10)" ::: "memory");
        BARRIER();
        READ_A(Pa, rb, 0);                 // ks0(kt+1), consumed next iter
        // W3: Qb(kt) ready (queue: Qb4 Pb4 SA2 -> leave 6)
        asm volatile("s_waitcnt vmcnt(6)" ::: "memory");
        CLUSTER(Qa, Qb);                   // ks1(kt)
        LOADB(Qb, kt + 1, 1);
        READ_A(Qa, rb, 1);                 // ks1(kt+1)
        const int n0 = rb, n1 = sb, n2 = cb;
        cb = n0; rb = n1; sb = n2;
    }

    // epilogue: out = (acc + bias) * scale
    // 32x32 C/D: col = lane&31, row = (g&3) + 8*(g>>2) + 4*(lane>>5)  [verified]
    const float scale = *sum_ptr * (1.0f / 67108864.0f);
    const int rbase = mb * 128 + wm * 64 + 4 * (lane >> 5);
    const int cbase = nb * 256 + wn * 128 + (lane & 31);
#pragma unroll
    for (int an = 0; an < 4; ++an) {
        const int col = cbase + an * 32;
        const float bb = bias[col];
#pragma unroll
        for (int am = 0; am < 2; ++am) {
            const int r0 = rbase + am * 32;
#pragma unroll
            for (int g = 0; g < 16; ++g) {
                const int row = r0 + (g & 3) + 8 * (g >> 2);
                out[(size_t)row * D_OUT + col] =
                    ((float)acc[am][an][g] + bb) * scale;
            }
        }
    }
}

extern "C" void kernel_launch(void* const* d_in, const int* in_sizes, int n_in,
                              void* d_out, int out_size, void* d_ws, size_t ws_size,
                              hipStream_t stream) {
    const float* x = (const float*)d_in[0];
    const float* W = (const float*)d_in[1];
    const float* b = (const float*)d_in[2];
    float* out = (float*)d_out;

    float* sum_ptr   = (float*)d_ws;                 // [0] result
    float* partials  = (float*)d_ws + 64;            // 4096 floats
    signed char* xs  = (signed char*)d_ws + 65536;
    signed char* wp  = xs + (size_t)TOKENS * D_IN;   // +64 MB

    pack_x_abssum<<<128 * 32, 256, 0, stream>>>(x, xs, partials);
    reduce_partials<<<1, 256, 0, stream>>>(partials, sum_ptr);
    pack_w_kernel<<<16 * 64, 256, 0, stream>>>(W, wp);
    bin_gemm<<<2048, 256, 0, stream>>>(xs, wp, b, sum_ptr, out);
}

// Round 10
// 354.973 us; speedup vs baseline: 1.2532x; 1.2532x over previous
//
#include <hip/hip_runtime.h>
#include <stdint.h>

#define TOKENS 16384
#define D_IN   4096
#define D_OUT  4096
#define NKT    64   // K-tiles of 64 i8

typedef int v4i  __attribute__((ext_vector_type(4)));
typedef int v16i __attribute__((ext_vector_type(16)));

__device__ __forceinline__ void gl_lds16(const void* g, void* l) {
    __builtin_amdgcn_global_load_lds(
        (const __attribute__((address_space(1))) void*)g,
        (__attribute__((address_space(3))) void*)l, 16, 0, 0);
}

#define BARRIER() __builtin_amdgcn_s_barrier()

__device__ __forceinline__ unsigned sgnb(float f) {
    return (unsigned)(unsigned char)(signed char)((f > 0.f) - (f < 0.f));
}

// ---------------------------------------------------------------------------
// Packed image for 32x32x32 i8 MFMA fragments (UNCHANGED since R6; verified
// absmax=0, SQ_LDS_BANK_CONFLICT=0).
// A: [mb(128)][kt(64)][u(4)][ks(2)][1KB]  row = mb*128+u*32+r, k = kt*64+ks*32+..
// B: [nb(16)][kt(64)][u(8)][ks(2)][1KB]
// Every 1KB fragment is lane-linear (lane*16): one coalesced wave-load for
// gl_lds and ds_read_b128.
// ---------------------------------------------------------------------------

__global__ __launch_bounds__(256) void pack_x_abssum(
        const float* __restrict__ x, signed char* __restrict__ xp,
        float* __restrict__ partials) {
    __shared__ unsigned char img[16384];   // two 8KB kt-units
    __shared__ float wsum[4];
    const int b   = blockIdx.x;            // 128*32 = 4096 blocks
    const int mb  = b >> 5;
    const int kt2 = b & 31;
    const int t   = threadIdx.x;
    const float* src = x + (size_t)mb * 128 * D_IN + kt2 * 128;
    float accum = 0.f;
#pragma unroll
    for (int p = 0; p < 16; ++p) {
        const int idx = p * 256 + t;       // 128 rows x 32 float4
        const int r   = idx >> 5;
        const int c4  = idx & 31;
        float4 v = *(const float4*)(src + (size_t)r * D_IN + c4 * 4);
        unsigned w = sgnb(v.x) | (sgnb(v.y) << 8) | (sgnb(v.z) << 16) | (sgnb(v.w) << 24);
        const int kl = (c4 * 4) & 63;
        const int off = ((c4 >= 16) ? 8192 : 0)
                      + (r >> 5) * 2048 + (kl >> 5) * 1024 + ((kl >> 4) & 1) * 512
                      + (r & 31) * 16 + (kl & 15);
        *(unsigned*)&img[off] = w;
        accum += fabsf(v.x) + fabsf(v.y) + fabsf(v.z) + fabsf(v.w);
    }
    __syncthreads();
    unsigned* dst = (unsigned*)(xp + ((size_t)mb * 64 + kt2 * 2) * 8192);
    const unsigned* s32 = (const unsigned*)img;
#pragma unroll
    for (int p = 0; p < 16; ++p) dst[p * 256 + t] = s32[p * 256 + t];
#pragma unroll
    for (int o = 32; o > 0; o >>= 1) accum += __shfl_down(accum, o);
    if ((t & 63) == 0) wsum[t >> 6] = accum;
    __syncthreads();
    if (t == 0) partials[b] = wsum[0] + wsum[1] + wsum[2] + wsum[3];
}

__global__ void reduce_partials(const float* __restrict__ p, float* __restrict__ s) {
    __shared__ float ws[4];
    float a = 0.f;
    for (int i = threadIdx.x; i < 4096; i += 256) a += p[i];
#pragma unroll
    for (int o = 32; o > 0; o >>= 1) a += __shfl_down(a, o);
    if ((threadIdx.x & 63) == 0) ws[threadIdx.x >> 6] = a;
    __syncthreads();
    if (threadIdx.x == 0) s[0] = ws[0] + ws[1] + ws[2] + ws[3];
}

__global__ __launch_bounds__(256) void pack_w_kernel(
        const float* __restrict__ wsrc, signed char* __restrict__ wp) {
    __shared__ unsigned char img[16384];
    const int b  = blockIdx.x;             // 16*64 = 1024 blocks
    const int nb = b >> 6;
    const int kt = b & 63;
    const int t  = threadIdx.x;
    const float* src = wsrc + (size_t)nb * 256 * D_IN + kt * 64;
#pragma unroll
    for (int p = 0; p < 16; ++p) {
        const int idx = p * 256 + t;       // 256 rows x 16 float4
        const int r   = idx >> 4;
        const int c4  = idx & 15;
        float4 v = *(const float4*)(src + (size_t)r * D_IN + c4 * 4);
        unsigned w = sgnb(v.x) | (sgnb(v.y) << 8) | (sgnb(v.z) << 16) | (sgnb(v.w) << 24);
        const int kl = c4 * 4;
        const int off = (r >> 5) * 2048 + (kl >> 5) * 1024 + ((kl >> 4) & 1) * 512
                      + (r & 31) * 16 + (kl & 15);
        *(unsigned*)&img[off] = w;
    }
    __syncthreads();
    unsigned* dst = (unsigned*)(wp + ((size_t)nb * 64 + kt) * 16384);
    const unsigned* s32 = (const unsigned*)img;
#pragma unroll
    for (int p = 0; p < 16; ++p) dst[p * 256 + t] = s32[p * 256 + t];
}

// ---------------------------------------------------------------------------
// 256x256 tile, BK=64, 4 waves (2Mx2N), WAVE-TILE 128x128 (am=4, an=4),
// mfma_i32_32x32x32. ONE block/CU, 1 wave/SIMD (512-reg budget).
// Rationale (R8 accounting): wall was MFMA(1171) + LDS(reads 1150 + writes
// 380) serialized. LDS reads scale with (am+an)/(am*an): 2x4 -> 0.75 KB/MFMA,
// 4x4 -> 0.5. This cuts LDS reads to 64 KB/slot (~768cy) and staging to
// 32 KB (~256cy). R8's cross-barrier rotation kept: every MFMA input is
// >=1 cluster old; reads burst-issue then the dependent-free 16-MFMA cluster
// occupies the matrix pipe while the LDS pipe drains the burst.
// Triple-buffered LDS 3x32KB = 96KB (forces 1 block/CU). Stage 2 tiles
// ahead (~2800cy cover). Sync: lgkmcnt(0) + vmcnt(8) + 1 barrier per tile.
// ---------------------------------------------------------------------------

#define STAGE(d, kt) do {                                               \
    signed char* L_ = (signed char*)&lds3[d][0];                        \
    const signed char* ga0_ = aG0 + (size_t)(kt) * 8192;                \
    const signed char* ga1_ = aG1 + (size_t)(kt) * 8192;                \
    const signed char* gb_  = bG  + (size_t)(kt) * 16384;               \
    gl_lds16(ga0_ + t16,         L_ + t16);                             \
    gl_lds16(ga0_ + 4096 + t16,  L_ + 4096 + t16);                      \
    gl_lds16(ga1_ + t16,         L_ + 8192 + t16);                      \
    gl_lds16(ga1_ + 4096 + t16,  L_ + 12288 + t16);                     \
    gl_lds16(gb_ + t16,          L_ + 16384 + t16);                     \
    gl_lds16(gb_ + 4096 + t16,   L_ + 20480 + t16);                     \
    gl_lds16(gb_ + 8192 + t16,   L_ + 24576 + t16);                     \
    gl_lds16(gb_ + 12288 + t16,  L_ + 28672 + t16);                     \
} while (0)

#define READ_KS(A4, B4, bufv, ks) do {                                  \
    const v4i* L_ = &lds3[bufv][0];                                     \
    A4[0] = L_[aof + (ks) * 64 + lane];                                 \
    A4[1] = L_[aof + 128 + (ks) * 64 + lane];                           \
    A4[2] = L_[aof + 256 + (ks) * 64 + lane];                           \
    A4[3] = L_[aof + 384 + (ks) * 64 + lane];                           \
    B4[0] = L_[bof + (ks) * 64 + lane];                                 \
    B4[1] = L_[bof + 128 + (ks) * 64 + lane];                           \
    B4[2] = L_[bof + 256 + (ks) * 64 + lane];                           \
    B4[3] = L_[bof + 384 + (ks) * 64 + lane];                           \
} while (0)

#define MFMA32(d, a, b) __builtin_amdgcn_mfma_i32_32x32x32_i8((a), (b), (d), 0, 0, 0)

#define CLUSTER16(A4, B4) do {                                          \
    _Pragma("unroll")                                                   \
    for (int am = 0; am < 4; ++am)                                      \
        _Pragma("unroll")                                               \
        for (int an = 0; an < 4; ++an)                                  \
            acc[am][an] = MFMA32(acc[am][an], A4[am], B4[an]);          \
} while (0)

__global__ __launch_bounds__(256, 1) void bin_gemm(
    const signed char* __restrict__ Ap, const signed char* __restrict__ Bp,
    const float* __restrict__ bias, const float* __restrict__ sum_ptr,
    float* __restrict__ out) {
    __shared__ v4i lds3[3][2048];          // 3 x 32KB = 96KB

    const int t    = threadIdx.x;          // 0..255
    const int t16  = t * 16;
    const int lane = t & 63;
    const int wid  = t >> 6;               // 0..3
    const int wm   = wid >> 1;             // M half: rows wm*128
    const int wn   = wid & 1;              // N half: cols wn*128
    const int aof  = wm * 512;             // A v4i base (wm image, 8KB)
    const int bof  = 1024 + wn * 512;      // B v4i base

    // XCD slice: xcd owns nb {2x,2x+1} (2MB packed B L2-resident).
    const int bid   = blockIdx.x;          // 1024 blocks
    const int xcd   = bid & 7;
    const int local = bid >> 3;            // 0..127
    const int nb    = xcd * 2 + (local & 1);   // 0..15
    const int mb    = local >> 1;              // 0..63  (256-row blocks)

    const signed char* aG0 = Ap + (size_t)(mb * 2) * 524288;      // 64kt x 8KB
    const signed char* aG1 = aG0 + 524288;
    const signed char* bG  = Bp + (size_t)nb * 64 * 16384;

    v16i acc[4][4];
#pragma unroll
    for (int i = 0; i < 4; ++i)
#pragma unroll
        for (int j = 0; j < 4; ++j) acc[i][j] = (v16i)(0);

    v4i A0[4], B0[4], A1[4], B1[4];        // ks0 / ks1 fragment banks

    // prologue: stage kt0,kt1; wait kt0; read tile-0 fragments
    STAGE(0, 0);
    STAGE(1, 1);
    asm volatile("s_waitcnt vmcnt(8)" ::: "memory");
    BARRIER();
    READ_KS(A0, B0, 0, 0);
    READ_KS(A1, B1, 0, 1);

    int cb = 0, rb = 1, sb = 2;
    for (int kt = 0; kt < NKT - 1; ++kt) {
        // ks0(kt): inputs read >=1 iteration ago
        CLUSTER16(A0, B0);
        if (kt < NKT - 2) STAGE(sb, kt + 2);
        asm volatile("s_waitcnt lgkmcnt(0)" ::: "memory");
        if (kt < NKT - 2) { asm volatile("s_waitcnt vmcnt(8)" ::: "memory"); }
        else              { asm volatile("s_waitcnt vmcnt(0)" ::: "memory"); }
        BARRIER();
        // next tile's ks0 fragments (consumed next iter; burst drains on LDS
        // pipe while the ks1 cluster owns the matrix pipe)
        READ_KS(A0, B0, rb, 0);
        CLUSTER16(A1, B1);                 // ks1(kt), inputs a full tile old
        READ_KS(A1, B1, rb, 1);
        const int n0 = rb, n1 = sb, n2 = cb;
        cb = n0; rb = n1; sb = n2;
    }
    // final tile
    CLUSTER16(A0, B0);
    CLUSTER16(A1, B1);

    // epilogue: out = (acc + bias) * scale
    // 32x32 C/D: col = lane&31, row = (g&3) + 8*(g>>2) + 4*(lane>>5)  [verified]
    const float scale = *sum_ptr * (1.0f / 67108864.0f);
    const int rbase = mb * 256 + wm * 128 + 4 * (lane >> 5);
    const int cbase = nb * 256 + wn * 128 + (lane & 31);
#pragma unroll
    for (int an = 0; an < 4; ++an) {
        const int col = cbase + an * 32;
        const float bb = bias[col];
#pragma unroll
        for (int am = 0; am < 4; ++am) {
            const int r0 = rbase + am * 32;
#pragma unroll
            for (int g = 0; g < 16; ++g) {
                const int row = r0 + (g & 3) + 8 * (g >> 2);
                out[(size_t)row * D_OUT + col] =
                    ((float)acc[am][an][g] + bb) * scale;
            }
        }
    }
}

extern "C" void kernel_launch(void* const* d_in, const int* in_sizes, int n_in,
                              void* d_out, int out_size, void* d_ws, size_t ws_size,
                              hipStream_t stream) {
    const float* x = (const float*)d_in[0];
    const float* W = (const float*)d_in[1];
    const float* b = (const float*)d_in[2];
    float* out = (float*)d_out;

    float* sum_ptr   = (float*)d_ws;                 // [0] result
    float* partials  = (float*)d_ws + 64;            // 4096 floats
    signed char* xs  = (signed char*)d_ws + 65536;
    signed char* wp  = xs + (size_t)TOKENS * D_IN;   // +64 MB

    pack_x_abssum<<<128 * 32, 256, 0, stream>>>(x, xs, partials);
    reduce_partials<<<1, 256, 0, stream>>>(partials, sum_ptr);
    pack_w_kernel<<<16 * 64, 256, 0, stream>>>(W, wp);
    bin_gemm<<<1024, 256, 0, stream>>>(xs, wp, b, sum_ptr, out);
}